// Round 3
// baseline (442.170 us; speedup 1.0000x reference)
//
#include <hip/hip_runtime.h>
#include <math.h>

// TopK router: logits = x @ W^T + b ; top-2 over E=64 ; sparse softmax.
// x: [T=16384, D=2048] f32, W: [64, 2048] f32, b: [64] f32.
// d_out: [T*64] router probs f32, then [T*2] top-k indices as f32.
//
// R3 redesign: x goes global->LDS via async DMA (global_load_lds width=16),
// per-wave-private double buffer, counted vmcnt(2) so the next chunk's DMA
// stays in flight under compute (no __syncthreads anywhere). Compute reads
// x as broadcast ds_read_b128 (lane=expert, uniform addr -> conflict-free);
// W is per-lane vector loads (L1/L2 resident, s_barrier phase-locks the
// block's 4 waves for L1 reuse). f64 accumulation every 32 elems (float4
// sub-chains of 8) keeps logit error ~5e-7 so top-2 indices match numpy.

#define RD 2048
#define RE 64
#define CHUNK 128                 // floats per token per chunk
#define NCHUNK (RD / CHUNK)       // 16
#define NWAVES 4
#define TPW 4                     // tokens per wave
#define TPB (NWAVES * TPW)        // 16 tokens per block

__device__ __forceinline__ void stage16(const float* g, float* l) {
    __builtin_amdgcn_global_load_lds(
        (const __attribute__((address_space(1))) void*)g,
        (__attribute__((address_space(3))) void*)l,
        16 /*bytes per lane*/, 0 /*offset*/, 0 /*aux*/);
}

__device__ __forceinline__ float4 fma4(const float4 a, const float4 b, float4 c) {
    c.x = fmaf(a.x, b.x, c.x);
    c.y = fmaf(a.y, b.y, c.y);
    c.z = fmaf(a.z, b.z, c.z);
    c.w = fmaf(a.w, b.w, c.w);
    return c;
}

__global__ __launch_bounds__(256, 4) void topk_router_kernel(
    const float* __restrict__ x,
    const float* __restrict__ W,
    const float* __restrict__ b,
    float* __restrict__ out_router,
    float* __restrict__ out_idx,
    int total_tokens)
{
    const int lane = threadIdx.x & 63;
    const int wv = __builtin_amdgcn_readfirstlane((int)(threadIdx.x >> 6));
    const int tok0 = blockIdx.x * TPB + wv * TPW;

    // per-wave private: xs[buf][wave][token][128 floats]; 16 KB total
    __shared__ __align__(16) float xs[2][NWAVES][TPW][CHUNK];

    // Stage instr i covers tokens tok0 + 2i + (lane>>5); lane&31 gives the
    // 16B slice within the 512B chunk-row (DMA writes LDS base + lane*16).
    const int tmax = total_tokens - 1;
    const int r0 = min(tok0 + 0 + (lane >> 5), tmax);
    const int r1 = min(tok0 + 2 + (lane >> 5), tmax);
    const float* gsrc0 = x + (size_t)r0 * RD + (lane & 31) * 4;
    const float* gsrc1 = x + (size_t)r1 * RD + (lane & 31) * 4;
    const float* wrow  = W + (size_t)lane * RD;

    double dacc[TPW] = {0.0, 0.0, 0.0, 0.0};

    auto compute = [&](int c, int bf) {
        const float* wc = wrow + c * CHUNK;
#pragma unroll
        for (int s = 0; s < 4; ++s) {      // 32-float sub-blocks
            const float4* wp = (const float4*)(wc + s * 32);
            const float4 w0 = wp[0], w1 = wp[1], w2 = wp[2], w3 = wp[3];
            const float4 w4 = wp[4], w5 = wp[5], w6 = wp[6], w7 = wp[7];
#pragma unroll
            for (int tt = 0; tt < TPW; ++tt) {
                const float4* xp = (const float4*)&xs[bf][wv][tt][s * 32];
                float4 a = make_float4(0.f, 0.f, 0.f, 0.f);
                a = fma4(xp[0], w0, a);
                a = fma4(xp[1], w1, a);
                a = fma4(xp[2], w2, a);
                a = fma4(xp[3], w3, a);
                a = fma4(xp[4], w4, a);
                a = fma4(xp[5], w5, a);
                a = fma4(xp[6], w6, a);
                a = fma4(xp[7], w7, a);
                const float h = (a.x + a.y) + (a.z + a.w);
                dacc[tt] += (double)h;
            }
        }
    };

    // prologue: stage chunk 0
    stage16(gsrc0, &xs[0][wv][0][0]);
    stage16(gsrc1, &xs[0][wv][2][0]);

    int bf = 0;
#pragma unroll 1
    for (int c = 0; c < NCHUNK - 1; ++c) {
        __builtin_amdgcn_sched_barrier(0);
        // stage next chunk into the other buffer (stays in flight: vmcnt(2))
        stage16(gsrc0 + (c + 1) * CHUNK, &xs[bf ^ 1][wv][0][0]);
        stage16(gsrc1 + (c + 1) * CHUNK, &xs[bf ^ 1][wv][2][0]);
        // wait until only the 2 just-issued DMAs remain -> chunk c is in LDS
        asm volatile("s_waitcnt vmcnt(2)" ::: "memory");
        __builtin_amdgcn_sched_barrier(0);
        compute(c, bf);
        // phase-lock the block's 4 waves so they share W through L1
        asm volatile("s_barrier" ::: "memory");
        bf ^= 1;
    }
    asm volatile("s_waitcnt vmcnt(0)" ::: "memory");
    __builtin_amdgcn_sched_barrier(0);
    compute(NCHUNK - 1, bf);

    // ---- epilogue: top-2 + sparse softmax, wave handles its own 4 tokens
    const double bias = (double)b[lane];

#pragma unroll
    for (int tt = 0; tt < TPW; ++tt) {
        const int token = tok0 + tt;
        if (token >= total_tokens) break;
        const double v = dacc[tt] + bias;

        // argmax #1 (value desc, tie -> lower lane)
        double bestv = v;
        int besti = lane;
#pragma unroll
        for (int off = 32; off > 0; off >>= 1) {
            double ov = __shfl_xor(bestv, off, 64);
            int oi = __shfl_xor(besti, off, 64);
            if (ov > bestv || (ov == bestv && oi < besti)) { bestv = ov; besti = oi; }
        }

        // argmax #2 excluding winner
        double v2 = (lane == besti) ? -INFINITY : v;
        double best2v = v2;
        int best2i = lane;
#pragma unroll
        for (int off = 32; off > 0; off >>= 1) {
            double ov = __shfl_xor(best2v, off, 64);
            int oi = __shfl_xor(best2i, off, 64);
            if (ov > best2v || (ov == best2v && oi < best2i)) { best2v = ov; best2i = oi; }
        }

        // 2-element softmax; all other experts exactly 0
        const float e2 = expf((float)(best2v - bestv));
        const float denom = 1.0f + e2;
        const float p1 = 1.0f / denom;
        const float p2 = e2 / denom;

        float outv = 0.0f;
        if (lane == besti) outv = p1;
        else if (lane == best2i) outv = p2;
        out_router[(size_t)token * RE + lane] = outv;

        if (lane == 0) {
            out_idx[(size_t)token * 2 + 0] = (float)besti;
            out_idx[(size_t)token * 2 + 1] = (float)best2i;
        }
    }
}

extern "C" void kernel_launch(void* const* d_in, const int* in_sizes, int n_in,
                              void* d_out, int out_size, void* d_ws, size_t ws_size,
                              hipStream_t stream) {
    const float* x = (const float*)d_in[0];
    const float* W = (const float*)d_in[1];
    const float* b = (const float*)d_in[2];

    const int E = in_sizes[2];                 // 64
    const int D = in_sizes[1] / E;             // 2048
    const int T = in_sizes[0] / D;             // 16384
    (void)E; (void)D;

    float* out_router = (float*)d_out;
    float* out_idx = out_router + (size_t)T * RE;

    const int grid = (T + TPB - 1) / TPB;      // 1024

    topk_router_kernel<<<grid, 256, 0, stream>>>(x, W, b, out_router, out_idx, T);
}